// Round 13
// baseline (253.169 us; speedup 1.0000x reference)
//
#include <hip/hip_runtime.h>
#include <hip/hip_bf16.h>
#include <math.h>

typedef __bf16 bf16x8 __attribute__((ext_vector_type(8)));
typedef float  f32x4  __attribute__((ext_vector_type(4)));
typedef short  s16x8  __attribute__((ext_vector_type(8)));
typedef unsigned int u32x2 __attribute__((ext_vector_type(2)));
typedef unsigned int u32x4 __attribute__((ext_vector_type(4)));

#define B_   4
#define N_   2048
#define C_   512
#define H_   8
#define DH_  64
#define HID_ 2048
#define MTOK 8192
#define LOG2E 1.4426950408889634f
#define QSCALE 0.18033688011112042f   // 0.125 * log2(e), folded into Q store

__device__ inline void gld_lds16(const void* g, void* l) {
  __builtin_amdgcn_global_load_lds((const __attribute__((address_space(1))) void*)g,
                                   (__attribute__((address_space(3))) void*)l,
                                   16, 0, 0);
}

// round-half-up f32->bf16 pack via v_perm: 3 VALU per pair
__device__ inline unsigned pack2_bf16(float a, float b) {
  unsigned pa = __builtin_bit_cast(unsigned, a) + 0x8000u;
  unsigned pb = __builtin_bit_cast(unsigned, b) + 0x8000u;
  return __builtin_amdgcn_perm(pb, pa, 0x07060302u);  // lo16=pa.hi, hi16=pb.hi
}

// RNE f32-pair -> packed bf16x2 in ONE VALU op (lo16=a, hi16=b)
__device__ inline unsigned cvtpk2(float a, float b) {
  unsigned r;
  asm("v_cvt_pk_bf16_f32 %0, %1, %2" : "=v"(r) : "v"(a), "v"(b));
  return r;
}

// ---------------- shared epilogue (per accumulator element) -------------------
// EPI 1: fout = acc + bias[col] + resid  (fp32)
// EPI 2: bout = gelu(acc + bias[col])    (bf16, tanh-form via exp2)
template<int EPI>
__device__ inline void epi_store(float v, int row, int col, int N,
    const float* __restrict__ bias, const float* __restrict__ resid,
    float* __restrict__ fout, __bf16* __restrict__ bout)
{
  if (EPI == 1) {
    const size_t idx = (size_t)row * N + col;
    fout[idx] = v + bias[col] + resid[idx];
  } else {
    // gelu, tanh form: g = x * t / (t + 1), t = exp2(2*c*log2e*(x + 0.044715x^3))
    const float xg = v + bias[col];
    const float x2 = xg * xg;
    const float u  = __builtin_fmaf(0.044715f * x2, xg, xg);
    const float t  = __builtin_amdgcn_exp2f(u * 2.3022082f);
    const float g  = xg * t * __builtin_amdgcn_rcpf(t + 1.0f);
    bout[(size_t)row * N + col] = (__bf16)g;
  }
}

// ---------------- gemm512: C = A[M,K]*B[N,K]^T, 512-thr, wave-tile 32x64 ------
// R10-best form (dbuf + __syncthreads). N=512 GEMMs (proj, fc2).
template<int EPI, int BN>
__global__ __launch_bounds__(512, 4) void gemm512(
    const __bf16* __restrict__ A, const __bf16* __restrict__ Bw,
    int M, int N, int K,
    const float* __restrict__ bias, const float* __restrict__ resid,
    float* __restrict__ fout, __bf16* __restrict__ bout)
{
  constexpr int NT = (BN == 128) ? 4 : 2;
  __shared__ __align__(16) __bf16 a_lds[2][128 * 32];
  __shared__ __align__(16) __bf16 b_lds[2][BN * 32];
  const int tid  = threadIdx.x;
  const int wave = tid >> 6, lane = tid & 63;
  const int quad = lane >> 4, l16 = lane & 15;
  const int bm = blockIdx.x * 128, bn = blockIdx.y * BN;
  const int wr = (wave >> 1) * 32;
  const int wc = (wave & 1) * (BN == 128 ? 64 : 32);
  const int srow = tid >> 2;        // 0..127 staging row
  const int c4   = lane & 3;        // 16B chunk

  const f32x4 fzero = {0.f, 0.f, 0.f, 0.f};
  f32x4 acc[2][NT];
  #pragma unroll
  for (int i = 0; i < 2; ++i)
    #pragma unroll
    for (int j = 0; j < NT; ++j) acc[i][j] = fzero;

  auto stage = [&](int buf, int k0) {
    gld_lds16(A + (size_t)(bm + srow) * K + k0 + c4 * 8, &a_lds[buf][wave * 512]);
    if (BN == 128 || wave < 4)
      gld_lds16(Bw + (size_t)(bn + srow) * K + k0 + c4 * 8, &b_lds[buf][wave * 512]);
  };

  const int nk = K >> 5;
  stage(0, 0);
  for (int ki = 0; ki < nk; ++ki) {
    const int cur = ki & 1;
    __syncthreads();
    if (ki + 1 < nk) stage(cur ^ 1, (ki + 1) << 5);
    bf16x8 af[2], bf[NT];
    #pragma unroll
    for (int t = 0; t < 2; ++t)
      af[t] = *(const bf16x8*)&a_lds[cur][(wr + t * 16 + l16) * 32 + quad * 8];
    #pragma unroll
    for (int t = 0; t < NT; ++t)
      bf[t] = *(const bf16x8*)&b_lds[cur][(wc + t * 16 + l16) * 32 + quad * 8];
    #pragma unroll
    for (int mt = 0; mt < 2; ++mt)
      #pragma unroll
      for (int nt = 0; nt < NT; ++nt)
        acc[mt][nt] = __builtin_amdgcn_mfma_f32_16x16x32_bf16(af[mt], bf[nt], acc[mt][nt], 0, 0, 0);
  }

  #pragma unroll
  for (int mt = 0; mt < 2; ++mt)
    #pragma unroll
    for (int nt = 0; nt < NT; ++nt)
      #pragma unroll
      for (int r = 0; r < 4; ++r)
        epi_store<EPI>(acc[mt][nt][r], bm + wr + mt * 16 + quad * 4 + r,
                       bn + wc + nt * 16 + l16, N, bias, resid, fout, bout);
}

// ---------------- gemm256: 128^2 tile, 4 waves 2x2, 64x64/wave. qkv + fc1 -----
// R13: single clean edit vs R10 — q/k blocks (bn<1024, block-uniform) compute
// mfma(B,A) instead of mfma(A,B): identical dot products, transposed placement,
// so acc r=0..3 walks d (contiguous in [b,h,n,d]) instead of n. 48 scalar 2B
// stores/thread -> 16 x 8B packed stores; h/d address chain collapses 4x.
// V blocks (bn>=1024) keep R10's unswapped order + packed V^T store.
template<int EPI>
__global__ __launch_bounds__(256, 3) void gemm256(
    const __bf16* __restrict__ A, const __bf16* __restrict__ Bw,
    int M, int N, int K,
    const float* __restrict__ bias, const float* __restrict__ resid,
    float* __restrict__ fout, __bf16* __restrict__ bout,
    __bf16* __restrict__ qo, __bf16* __restrict__ ko, __bf16* __restrict__ vo)
{
  __shared__ __align__(16) __bf16 a_lds[2][128 * 32];
  __shared__ __align__(16) __bf16 b_lds[2][128 * 32];
  const int tid  = threadIdx.x;
  const int wave = tid >> 6, lane = tid & 63;
  const int quad = lane >> 4, l16 = lane & 15;
  const int bm = blockIdx.x * 128, bn = blockIdx.y * 128;
  const int wr = (wave >> 1) * 64;
  const int wc = (wave & 1) * 64;
  const int srow = tid >> 2;        // 0..63 staging row
  const int c4   = lane & 3;        // 16B chunk
  const bool swapqk = (EPI == 0) && (bn < 1024);

  const f32x4 fzero = {0.f, 0.f, 0.f, 0.f};
  f32x4 acc[4][4];
  #pragma unroll
  for (int i = 0; i < 4; ++i)
    #pragma unroll
    for (int j = 0; j < 4; ++j) acc[i][j] = fzero;

  auto stage = [&](int buf, int k0) {
    gld_lds16(A + (size_t)(bm + srow) * K + k0 + c4 * 8, &a_lds[buf][wave * 512]);
    gld_lds16(A + (size_t)(bm + 64 + srow) * K + k0 + c4 * 8, &a_lds[buf][2048 + wave * 512]);
    gld_lds16(Bw + (size_t)(bn + srow) * K + k0 + c4 * 8, &b_lds[buf][wave * 512]);
    gld_lds16(Bw + (size_t)(bn + 64 + srow) * K + k0 + c4 * 8, &b_lds[buf][2048 + wave * 512]);
  };

  const int nk = K >> 5;
  stage(0, 0);
  for (int ki = 0; ki < nk; ++ki) {
    const int cur = ki & 1;
    __syncthreads();
    if (ki + 1 < nk) stage(cur ^ 1, (ki + 1) << 5);
    bf16x8 af[4], bf[4];
    #pragma unroll
    for (int t = 0; t < 4; ++t)
      af[t] = *(const bf16x8*)&a_lds[cur][(wr + t * 16 + l16) * 32 + quad * 8];
    #pragma unroll
    for (int t = 0; t < 4; ++t)
      bf[t] = *(const bf16x8*)&b_lds[cur][(wc + t * 16 + l16) * 32 + quad * 8];
    if (swapqk) {
      #pragma unroll
      for (int mt = 0; mt < 4; ++mt)
        #pragma unroll
        for (int nt = 0; nt < 4; ++nt)
          acc[mt][nt] = __builtin_amdgcn_mfma_f32_16x16x32_bf16(bf[nt], af[mt], acc[mt][nt], 0, 0, 0);
    } else {
      #pragma unroll
      for (int mt = 0; mt < 4; ++mt)
        #pragma unroll
        for (int nt = 0; nt < 4; ++nt)
          acc[mt][nt] = __builtin_amdgcn_mfma_f32_16x16x32_bf16(af[mt], bf[nt], acc[mt][nt], 0, 0, 0);
    }
  }

  if (EPI == 0) {
    const int b = bm >> 11;
    if (bn >= 1024) {
      // V block (unswapped): vo[b][h][d][n]; r=0..3 = 4 consecutive n at fixed d.
      #pragma unroll
      for (int mt = 0; mt < 4; ++mt) {
        const int n = (bm + wr + mt * 16 + quad * 4) & (N_ - 1);
        #pragma unroll
        for (int nt = 0; nt < 4; ++nt) {
          const int col = bn + wc + nt * 16 + l16;
          const int h = (col >> 6) & (H_ - 1), d = col & (DH_ - 1);
          u32x2 pkd;
          pkd.x = cvtpk2(acc[mt][nt][0], acc[mt][nt][1]);
          pkd.y = cvtpk2(acc[mt][nt][2], acc[mt][nt][3]);
          *(u32x2*)(vo + ((((size_t)b * H_ + h) * DH_ + d) << 11) + n) = pkd;
        }
      }
    } else {
      // q/k block (swapped acc = C^T): w = bn+wc+nt*16+quad*4+r, n = bm+wr+mt*16+l16.
      const int sqk = bn >> 9;                    // 0 = q, 1 = k (block-uniform)
      __bf16* dst = sqk ? ko : qo;
      const float sc = sqk ? 1.0f : QSCALE;
      #pragma unroll
      for (int mt = 0; mt < 4; ++mt) {
        const int n = (bm + wr + mt * 16 + l16) & (N_ - 1);
        #pragma unroll
        for (int nt = 0; nt < 4; ++nt) {
          const int w = bn + wc + nt * 16 + quad * 4;
          const int h = (w >> 6) & (H_ - 1), d = w & (DH_ - 1);
          u32x2 pkd;
          pkd.x = cvtpk2(acc[mt][nt][0] * sc, acc[mt][nt][1] * sc);
          pkd.y = cvtpk2(acc[mt][nt][2] * sc, acc[mt][nt][3] * sc);
          *(u32x2*)(dst + ((((size_t)b * H_ + h) * N_ + n) << 6) + d) = pkd;
        }
      }
    }
  } else {
    #pragma unroll
    for (int mt = 0; mt < 4; ++mt)
      #pragma unroll
      for (int nt = 0; nt < 4; ++nt)
        #pragma unroll
        for (int r = 0; r < 4; ++r)
          epi_store<EPI>(acc[mt][nt][r], bm + wr + mt * 16 + quad * 4 + r,
                         bn + wc + nt * 16 + l16, N, bias, resid, fout, bout);
  }
}

// ---------------- LayerNorm device helper: one wave per token -----------------
__device__ inline void ln_row(const float* __restrict__ xr,
                              const float* __restrict__ w, const float* __restrict__ b,
                              __bf16* __restrict__ orow, int lane)
{
  float4 v0 = ((const float4*)xr)[lane];
  float4 v1 = ((const float4*)xr)[lane + 64];
  float s = v0.x + v0.y + v0.z + v0.w + v1.x + v1.y + v1.z + v1.w;
  float q = v0.x*v0.x + v0.y*v0.y + v0.z*v0.z + v0.w*v0.w
          + v1.x*v1.x + v1.y*v1.y + v1.z*v1.z + v1.w*v1.w;
  #pragma unroll
  for (int off = 32; off >= 1; off >>= 1) {
    s += __shfl_xor(s, off, 64);
    q += __shfl_xor(q, off, 64);
  }
  const float mu  = s * (1.0f / C_);
  const float var = q * (1.0f / C_) - mu * mu;
  const float rs  = rsqrtf(var + 1e-5f);
  float4 w0 = ((const float4*)w)[lane], w1 = ((const float4*)w)[lane + 64];
  float4 b0 = ((const float4*)b)[lane], b1 = ((const float4*)b)[lane + 64];
  const int c0 = lane * 4;
  orow[c0 + 0]       = (__bf16)((v0.x - mu) * rs * w0.x + b0.x);
  orow[c0 + 1]       = (__bf16)((v0.y - mu) * rs * w0.y + b0.y);
  orow[c0 + 2]       = (__bf16)((v0.z - mu) * rs * w0.z + b0.z);
  orow[c0 + 3]       = (__bf16)((v0.w - mu) * rs * w0.w + b0.w);
  orow[256 + c0 + 0] = (__bf16)((v1.x - mu) * rs * w1.x + b1.x);
  orow[256 + c0 + 1] = (__bf16)((v1.y - mu) * rs * w1.y + b1.y);
  orow[256 + c0 + 2] = (__bf16)((v1.z - mu) * rs * w1.z + b1.z);
  orow[256 + c0 + 3] = (__bf16)((v1.w - mu) * rs * w1.w + b1.w);
}

// ---------------- standalone LN (for ln2) -------------------------------------
__global__ __launch_bounds__(256) void ln_kernel(
    const float* __restrict__ x, const float* __restrict__ w,
    const float* __restrict__ b, __bf16* __restrict__ out)
{
  const int wave = threadIdx.x >> 6, lane = threadIdx.x & 63;
  const int tok  = blockIdx.x * 4 + wave;
  ln_row(x + (size_t)tok * C_, w, b, out + (size_t)tok * C_, lane);
}

// ---------------- merged: weight cast (blocks 0..3071) + ln1 (3072..5119) -----
__global__ __launch_bounds__(256) void castln_kernel(
    const float* __restrict__ s0, const float* __restrict__ s1,
    const float* __restrict__ s2, const float* __restrict__ s3,
    __bf16* __restrict__ d0, __bf16* __restrict__ d1,
    __bf16* __restrict__ d2, __bf16* __restrict__ d3,
    const float* __restrict__ x, const float* __restrict__ n1w,
    const float* __restrict__ n1b, __bf16* __restrict__ hbuf)
{
  if (blockIdx.x < 3072) {
    const int i = (blockIdx.x * 256 + threadIdx.x) * 4;
    const float* s; __bf16* d; int off;
    if (i < 786432)       { s = s0; d = d0; off = i; }
    else if (i < 1048576) { s = s1; d = d1; off = i - 786432; }
    else if (i < 2097152) { s = s2; d = d2; off = i - 1048576; }
    else                  { s = s3; d = d3; off = i - 2097152; }
    const float4 v = *(const float4*)(s + off);
    u32x2 pk;
    pk.x = pack2_bf16(v.x, v.y);
    pk.y = pack2_bf16(v.z, v.w);
    *(u32x2*)(d + off) = pk;
  } else {
    const int wave = threadIdx.x >> 6, lane = threadIdx.x & 63;
    const int tok  = (blockIdx.x - 3072) * 4 + wave;
    ln_row(x + (size_t)tok * C_, n1w, n1b, hbuf + (size_t)tok * C_, lane);
  }
}

// ---------------- flash attention v13 (frozen at R4; single 512-block launch) -
// R12's in-kernel weight-cast prologue cost +4.5us in flash (cast traffic
// serialized against the K/V DMA drains) — removed, castln restored to 4-way.
__global__ __launch_bounds__(256, 2) void flash_kernel(
    const __bf16* __restrict__ qb, const __bf16* __restrict__ kb,
    const __bf16* __restrict__ vtg, const float* __restrict__ rpb,
    __bf16* __restrict__ outb, int bh0)
{
  __shared__ __align__(16) __bf16 kbufs[2][8192];   // [buf][2 ks][128 key(perm)][32 d]
  __shared__ __align__(16) __bf16 vbufs[2][8192];   // [buf][4 ks2][64 d][32 key], swizzled
  __shared__ __align__(16) float  biasF[2192];      // bias[i + boff] * LOG2E, f32
  const int tid  = threadIdx.x;
  const int wave = tid >> 6, lane = tid & 63;
  const int quad = lane >> 4, l16 = lane & 15;
  const int bh = blockIdx.y + bh0, h = bh & (H_ - 1);
  const int q0 = blockIdx.x * 128;
  const int boff = 1920 - q0;

  for (int i = tid; i < 2192; i += 256) {
    int ridx = i + boff;
    ridx = ridx < 0 ? 0 : (ridx > 2 * N_ - 2 ? 2 * N_ - 2 : ridx);
    biasF[i] = rpb[(size_t)ridx * H_ + h] * LOG2E;
  }

  const __bf16* qptr = qb  + (size_t)bh * N_ * DH_;
  const __bf16* kptr = kb  + (size_t)bh * N_ * DH_;
  const __bf16* vtp  = vtg + (size_t)bh * N_ * DH_;

  bf16x8 qf[2][2];
  #pragma unroll
  for (int mt = 0; mt < 2; ++mt)
    #pragma unroll
    for (int ks = 0; ks < 2; ++ks)
      qf[mt][ks] = *(const bf16x8*)(qptr +
          (size_t)(q0 + wave * 32 + mt * 16 + l16) * DH_ + ks * 32 + quad * 8);

  const f32x4 fzero = {0.f, 0.f, 0.f, 0.f};
  f32x4 o[2][4];
  f32x4 la[2] = {fzero, fzero};     // l accumulators (ones-MFMA)
  #pragma unroll
  for (int mt = 0; mt < 2; ++mt)
    #pragma unroll
    for (int dt = 0; dt < 4; ++dt) o[mt][dt] = fzero;

  const s16x8 ones_s = {(short)0x3F80, (short)0x3F80, (short)0x3F80, (short)0x3F80,
                        (short)0x3F80, (short)0x3F80, (short)0x3F80, (short)0x3F80};
  const bf16x8 ones8 = __builtin_bit_cast(bf16x8, ones_s);

  const int slr = lane >> 2;
  const int slc = lane & 3;
  const int vswz = (slr & 3) ^ ((slr >> 2) & 3);
  const int rswz = (l16 & 3) ^ ((l16 >> 2) & 3);

  auto stageK = [&](int buf, int kcn) {
    #pragma unroll
    for (int j = 0; j < 4; ++j) {
      const int idx = wave * 4 + j;
      const int ks = idx & 1, g = idx >> 1;
      // permuted source row: within each 32-key group, LDS row m holds global
      // key [b3 b2 b4 b1 b0] so that S-tile pairs yield x32 B-frag key order.
      const int R = g * 16 + slr;
      const int m = R & 31;
      const int pr = (R & ~31) | (((m >> 2) & 3) << 3) | (((m >> 4) & 1) << 2) | (m & 3);
      gld_lds16(kptr + (size_t)(kcn + pr) * DH_ + ks * 32 + slc * 8,
                &kbufs[buf][ks * 4096 + g * 512]);
    }
  };
  auto stageV = [&](int buf, int kcn) {
    #pragma unroll
    for (int j = 0; j < 4; ++j) {
      const int idx = wave * 4 + j;
      const int ks2 = idx & 3, gg = idx >> 2;
      gld_lds16(vtp + (size_t)(gg * 16 + slr) * N_ + kcn + ks2 * 32 + (slc ^ vswz) * 8,
                &vbufs[buf][ks2 * 2048 + gg * 512]);
    }
  };

  const int bb0 = 127 + quad * 8 - wave * 32 - l16;   // permuted-key bias base

  stageK(0, 0);
  stageV(0, 0);
  for (int it = 0; it < 16; ++it) {
    const int cur = it & 1;
    const int kc = it << 7;
    __syncthreads();   // buf[cur] DMA complete; buf[cur] reads of iter it-2 done
    if (it < 15) {
      stageK(cur ^ 1, kc + 128);
      stageV(cur ^ 1, kc + 128);
    }

    // V-frag issue-early: depends only on the barrier; lands during QK/softmax.
    bf16x8 vv[16];
    #pragma unroll
    for (int c = 0; c < 4; ++c)
      #pragma unroll
      for (int dt = 0; dt < 4; ++dt)
        vv[c * 4 + dt] = *(const bf16x8*)&vbufs[cur][c * 2048 + l16 * 32 +
                                                     (quad ^ rswz) * 8 + dt * 512];

    unsigned pk[2][8][2];
    const float* bp = biasF + kc + bb0;
    #pragma unroll
    for (int ct = 0; ct < 8; ++ct) {
      // permuted global key for (ct, quad, r): kc + (ct>>1)*32 + (ct&1)*4 + quad*8 + r
      const int co = (ct >> 1) * 32 + (ct & 1) * 4;
      const bf16x8 kf0 = *(const bf16x8*)&kbufs[cur][(ct * 16 + l16) * 32 + quad * 8];
      const bf16x8 kf1 = *(const bf16x8*)&kbufs[cur][4096 + (ct * 16 + l16) * 32 + quad * 8];
      const f32x4 c0 = {bp[co], bp[co + 1], bp[co + 2], bp[co + 3]};
      const f32x4 c1 = {bp[co - 16], bp[co - 15], bp[co - 14], bp[co - 13]};
      f32x4 s0 = __builtin_amdgcn_mfma_f32_16x16x32_bf16(kf0, qf[0][0], c0, 0, 0, 0);
      s0 = __builtin_amdgcn_mfma_f32_16x16x32_bf16(kf1, qf[0][1], s0, 0, 0, 0);
      f32x4 s1 = __builtin_amdgcn_mfma_f32_16x16x32_bf16(kf0, qf[1][0], c1, 0, 0, 0);
      s1 = __builtin_amdgcn_mfma_f32_16x16x32_bf16(kf1, qf[1][1], s1, 0, 0, 0);
      {
        const float p0 = __builtin_amdgcn_exp2f(s0[0]);
        const float p1 = __builtin_amdgcn_exp2f(s0[1]);
        const float p2 = __builtin_amdgcn_exp2f(s0[2]);
        const float p3 = __builtin_amdgcn_exp2f(s0[3]);
        pk[0][ct][0] = cvtpk2(p0, p1);
        pk[0][ct][1] = cvtpk2(p2, p3);
      }
      {
        const float p0 = __builtin_amdgcn_exp2f(s1[0]);
        const float p1 = __builtin_amdgcn_exp2f(s1[1]);
        const float p2 = __builtin_amdgcn_exp2f(s1[2]);
        const float p3 = __builtin_amdgcn_exp2f(s1[3]);
        pk[1][ct][0] = cvtpk2(p0, p1);
        pk[1][ct][1] = cvtpk2(p2, p3);
      }
    }

    // PV + l-accum on 16x16x32: pf8 = [tileA r0..3 | tileB r0..3] = keys quad*8+0..7
    #pragma unroll
    for (int c = 0; c < 4; ++c) {
      const u32x4 t0 = {pk[0][2*c][0], pk[0][2*c][1], pk[0][2*c+1][0], pk[0][2*c+1][1]};
      const u32x4 t1 = {pk[1][2*c][0], pk[1][2*c][1], pk[1][2*c+1][0], pk[1][2*c+1][1]};
      const bf16x8 pf0 = __builtin_bit_cast(bf16x8, t0);
      const bf16x8 pf1 = __builtin_bit_cast(bf16x8, t1);
      la[0] = __builtin_amdgcn_mfma_f32_16x16x32_bf16(ones8, pf0, la[0], 0, 0, 0);
      la[1] = __builtin_amdgcn_mfma_f32_16x16x32_bf16(ones8, pf1, la[1], 0, 0, 0);
      #pragma unroll
      for (int dt = 0; dt < 4; ++dt) {
        const bf16x8 vf = vv[c * 4 + dt];
        o[0][dt] = __builtin_amdgcn_mfma_f32_16x16x32_bf16(vf, pf0, o[0][dt], 0, 0, 0);
        o[1][dt] = __builtin_amdgcn_mfma_f32_16x16x32_bf16(vf, pf1, o[1][dt], 0, 0, 0);
      }
    }
  }

  const int b = bh >> 3;
  #pragma unroll
  for (int mt = 0; mt < 2; ++mt) {
    const float inv = 1.0f / la[mt][0];
    const int qg = q0 + wave * 32 + mt * 16 + l16;
    __bf16* orow = outb + ((size_t)(b * N_ + qg)) * C_ + h * DH_ + quad * 4;
    #pragma unroll
    for (int dt = 0; dt < 4; ++dt) {
      u32x2 pkd;
      pkd.x = cvtpk2(o[mt][dt][0] * inv, o[mt][dt][1] * inv);
      pkd.y = cvtpk2(o[mt][dt][2] * inv, o[mt][dt][3] * inv);
      *(u32x2*)(orow + dt * 16) = pkd;
    }
  }
}

extern "C" void kernel_launch(void* const* d_in, const int* in_sizes, int n_in,
                              void* d_out, int out_size, void* d_ws, size_t ws_size,
                              hipStream_t stream)
{
  const float* x      = (const float*)d_in[0];
  const float* qkv_w  = (const float*)d_in[1];
  const float* proj_w = (const float*)d_in[2];
  const float* proj_b = (const float*)d_in[3];
  const float* rpb    = (const float*)d_in[4];
  const float* n1w    = (const float*)d_in[5];
  const float* n1b    = (const float*)d_in[6];
  const float* n2w    = (const float*)d_in[7];
  const float* n2b    = (const float*)d_in[8];
  const float* fc1_w  = (const float*)d_in[9];
  const float* fc1_b  = (const float*)d_in[10];
  const float* fc2_w  = (const float*)d_in[11];
  const float* fc2_b  = (const float*)d_in[12];

  char* ws = (char*)d_ws;
  __bf16* hbuf = (__bf16*)(ws + 0);          // 8192*512  bf16
  __bf16* qbuf = (__bf16*)(ws + 8388608);    // [b,h,n,d] (pre-scaled by QSCALE)
  __bf16* kbuf = (__bf16*)(ws + 16777216);   // [b,h,n,d]
  __bf16* vbuf = (__bf16*)(ws + 25165824);   // V^T [b,h,d,n]
  __bf16* gelu = (__bf16*)(ws + 0);          // 8192*2048 bf16 (alias)
  __bf16* wq   = (__bf16*)(ws + 33554432);
  __bf16* wp   = (__bf16*)(ws + 35127296);
  __bf16* w1   = (__bf16*)(ws + 35651584);
  __bf16* w2   = (__bf16*)(ws + 37748736);
  __bf16* attn = (__bf16*)(ws + 39845888);   // 8192*512 bf16
  __bf16* h2in = attn;                       // alias
  float*  x1   = (float*)(ws + 48234496);    // 8192*512 fp32
  float*  outp = (float*)d_out;

  // cast (3072 blocks) + ln1 (2048 blocks) in one launch
  castln_kernel<<<5120, 256, 0, stream>>>(qkv_w, proj_w, fc1_w, fc2_w,
      wq, wp, w1, w2, x, n1w, n1b, hbuf);

  gemm256<0><<<dim3(64, 12), 256, 0, stream>>>(hbuf, wq, MTOK, 1536, 512,
      nullptr, nullptr, nullptr, nullptr, qbuf, kbuf, vbuf);

  flash_kernel<<<dim3(16, 32), 256, 0, stream>>>(qbuf, kbuf, vbuf, rpb, attn, 0);

  gemm512<1, 64><<<dim3(64, 8), 512, 0, stream>>>(attn, wp, MTOK, 512, 512,
      proj_b, x, x1, nullptr);

  ln_kernel<<<2048, 256, 0, stream>>>(x1, n2w, n2b, h2in);

  gemm256<2><<<dim3(64, 16), 256, 0, stream>>>(h2in, w1, MTOK, 2048, 512,
      fc1_b, nullptr, nullptr, gelu, nullptr, nullptr, nullptr);

  gemm512<1, 64><<<dim3(64, 8), 512, 0, stream>>>(gelu, w2, MTOK, 512, 2048,
      fc2_b, x1, outp, nullptr);
}

// Round 14
// 239.460 us; speedup vs baseline: 1.0572x; 1.0572x over previous
//
#include <hip/hip_runtime.h>
#include <hip/hip_bf16.h>
#include <math.h>

typedef __bf16 bf16x8 __attribute__((ext_vector_type(8)));
typedef float  f32x4  __attribute__((ext_vector_type(4)));
typedef short  s16x8  __attribute__((ext_vector_type(8)));
typedef unsigned int u32x2 __attribute__((ext_vector_type(2)));
typedef unsigned int u32x4 __attribute__((ext_vector_type(4)));

#define B_   4
#define N_   2048
#define C_   512
#define H_   8
#define DH_  64
#define HID_ 2048
#define MTOK 8192
#define LOG2E 1.4426950408889634f
#define QSCALE 0.18033688011112042f   // 0.125 * log2(e), folded into Q store

__device__ inline void gld_lds16(const void* g, void* l) {
  __builtin_amdgcn_global_load_lds((const __attribute__((address_space(1))) void*)g,
                                   (__attribute__((address_space(3))) void*)l,
                                   16, 0, 0);
}

// round-half-up f32->bf16 pack via v_perm: 3 VALU per pair
__device__ inline unsigned pack2_bf16(float a, float b) {
  unsigned pa = __builtin_bit_cast(unsigned, a) + 0x8000u;
  unsigned pb = __builtin_bit_cast(unsigned, b) + 0x8000u;
  return __builtin_amdgcn_perm(pb, pa, 0x07060302u);  // lo16=pa.hi, hi16=pb.hi
}

// RNE f32-pair -> packed bf16x2 in ONE VALU op (lo16=a, hi16=b)
__device__ inline unsigned cvtpk2(float a, float b) {
  unsigned r;
  asm("v_cvt_pk_bf16_f32 %0, %1, %2" : "=v"(r) : "v"(a), "v"(b));
  return r;
}

// ---------------- shared epilogue (per accumulator element) -------------------
// EPI 0: qkv split-store (q/k scalar path; V handled packed at caller)
// EPI 1: fout = acc + bias[col] + resid  (fp32)
// EPI 2: bout = gelu(acc + bias[col])    (bf16, tanh-form via exp2)
// R13 lesson: q/k operand-swap packed store (mfma(B,A) + 8B stores) cost
// +12.7us — the swap breaks af-operand reuse across the nt loop. Scalar q/k
// stores are the measured-best form. Do not re-apply the swap.
template<int EPI>
__device__ inline void epi_store(float v, int row, int col, int N,
    const float* __restrict__ bias, const float* __restrict__ resid,
    float* __restrict__ fout, __bf16* __restrict__ bout,
    __bf16* __restrict__ qo, __bf16* __restrict__ ko, __bf16* __restrict__ vo)
{
  if (EPI == 0) {
    const int b = row >> 11, n = row & (N_ - 1);
    const int s = col >> 9, h = (col >> 6) & (H_ - 1), d = col & (DH_ - 1);
    if (s == 2) {
      vo[((((size_t)b * H_ + h) * DH_ + d) << 11) + n] = (__bf16)v;
    } else if (s == 1) {
      ko[((((size_t)b * H_ + h) * N_ + n) << 6) + d] = (__bf16)v;
    } else {
      qo[((((size_t)b * H_ + h) * N_ + n) << 6) + d] = (__bf16)(v * QSCALE);
    }
  } else if (EPI == 1) {
    const size_t idx = (size_t)row * N + col;
    fout[idx] = v + bias[col] + resid[idx];
  } else {
    // gelu, tanh form: g = x * t / (t + 1), t = exp2(2*c*log2e*(x + 0.044715x^3))
    const float xg = v + bias[col];
    const float x2 = xg * xg;
    const float u  = __builtin_fmaf(0.044715f * x2, xg, xg);
    const float t  = __builtin_amdgcn_exp2f(u * 2.3022082f);
    const float g  = xg * t * __builtin_amdgcn_rcpf(t + 1.0f);
    bout[(size_t)row * N + col] = (__bf16)g;
  }
}

// ---------------- gemm512: C = A[M,K]*B[N,K]^T, 512-thr, wave-tile 32x64 ------
// R10-best form (dbuf + __syncthreads). N=512 GEMMs (proj, fc2).
// R11 counted-vmcnt: +7us (regressed). R6 rotation / R7 xcd-remap: null.
template<int EPI, int BN>
__global__ __launch_bounds__(512, 4) void gemm512(
    const __bf16* __restrict__ A, const __bf16* __restrict__ Bw,
    int M, int N, int K,
    const float* __restrict__ bias, const float* __restrict__ resid,
    float* __restrict__ fout, __bf16* __restrict__ bout,
    __bf16* __restrict__ qo, __bf16* __restrict__ ko, __bf16* __restrict__ vo)
{
  constexpr int NT = (BN == 128) ? 4 : 2;
  __shared__ __align__(16) __bf16 a_lds[2][128 * 32];
  __shared__ __align__(16) __bf16 b_lds[2][BN * 32];
  const int tid  = threadIdx.x;
  const int wave = tid >> 6, lane = tid & 63;
  const int quad = lane >> 4, l16 = lane & 15;
  const int bm = blockIdx.x * 128, bn = blockIdx.y * BN;
  const int wr = (wave >> 1) * 32;
  const int wc = (wave & 1) * (BN == 128 ? 64 : 32);
  const int srow = tid >> 2;        // 0..127 staging row
  const int c4   = lane & 3;        // 16B chunk

  const f32x4 fzero = {0.f, 0.f, 0.f, 0.f};
  f32x4 acc[2][NT];
  #pragma unroll
  for (int i = 0; i < 2; ++i)
    #pragma unroll
    for (int j = 0; j < NT; ++j) acc[i][j] = fzero;

  auto stage = [&](int buf, int k0) {
    gld_lds16(A + (size_t)(bm + srow) * K + k0 + c4 * 8, &a_lds[buf][wave * 512]);
    if (BN == 128 || wave < 4)
      gld_lds16(Bw + (size_t)(bn + srow) * K + k0 + c4 * 8, &b_lds[buf][wave * 512]);
  };

  const int nk = K >> 5;
  stage(0, 0);
  for (int ki = 0; ki < nk; ++ki) {
    const int cur = ki & 1;
    __syncthreads();
    if (ki + 1 < nk) stage(cur ^ 1, (ki + 1) << 5);
    bf16x8 af[2], bf[NT];
    #pragma unroll
    for (int t = 0; t < 2; ++t)
      af[t] = *(const bf16x8*)&a_lds[cur][(wr + t * 16 + l16) * 32 + quad * 8];
    #pragma unroll
    for (int t = 0; t < NT; ++t)
      bf[t] = *(const bf16x8*)&b_lds[cur][(wc + t * 16 + l16) * 32 + quad * 8];
    #pragma unroll
    for (int mt = 0; mt < 2; ++mt)
      #pragma unroll
      for (int nt = 0; nt < NT; ++nt)
        acc[mt][nt] = __builtin_amdgcn_mfma_f32_16x16x32_bf16(af[mt], bf[nt], acc[mt][nt], 0, 0, 0);
  }

  #pragma unroll
  for (int mt = 0; mt < 2; ++mt)
    #pragma unroll
    for (int nt = 0; nt < NT; ++nt)
      #pragma unroll
      for (int r = 0; r < 4; ++r)
        epi_store<EPI>(acc[mt][nt][r], bm + wr + mt * 16 + quad * 4 + r,
                       bn + wc + nt * 16 + l16, N,
                       bias, resid, fout, bout, qo, ko, vo);
}

// ---------------- gemm256: 128^2 tile, 4 waves 2x2, 64x64/wave. qkv + fc1 -----
// R10-best form: unswapped MFMA; V blocks (bn>=1024) use the packed V^T store
// (r=0..3 = 4 consecutive n at fixed d -> one 8B store); q/k blocks scalar.
template<int EPI>
__global__ __launch_bounds__(256, 3) void gemm256(
    const __bf16* __restrict__ A, const __bf16* __restrict__ Bw,
    int M, int N, int K,
    const float* __restrict__ bias, const float* __restrict__ resid,
    float* __restrict__ fout, __bf16* __restrict__ bout,
    __bf16* __restrict__ qo, __bf16* __restrict__ ko, __bf16* __restrict__ vo)
{
  __shared__ __align__(16) __bf16 a_lds[2][128 * 32];
  __shared__ __align__(16) __bf16 b_lds[2][128 * 32];
  const int tid  = threadIdx.x;
  const int wave = tid >> 6, lane = tid & 63;
  const int quad = lane >> 4, l16 = lane & 15;
  const int bm = blockIdx.x * 128, bn = blockIdx.y * 128;
  const int wr = (wave >> 1) * 64;
  const int wc = (wave & 1) * 64;
  const int srow = tid >> 2;        // 0..63 staging row
  const int c4   = lane & 3;        // 16B chunk

  const f32x4 fzero = {0.f, 0.f, 0.f, 0.f};
  f32x4 acc[4][4];
  #pragma unroll
  for (int i = 0; i < 4; ++i)
    #pragma unroll
    for (int j = 0; j < 4; ++j) acc[i][j] = fzero;

  auto stage = [&](int buf, int k0) {
    gld_lds16(A + (size_t)(bm + srow) * K + k0 + c4 * 8, &a_lds[buf][wave * 512]);
    gld_lds16(A + (size_t)(bm + 64 + srow) * K + k0 + c4 * 8, &a_lds[buf][2048 + wave * 512]);
    gld_lds16(Bw + (size_t)(bn + srow) * K + k0 + c4 * 8, &b_lds[buf][wave * 512]);
    gld_lds16(Bw + (size_t)(bn + 64 + srow) * K + k0 + c4 * 8, &b_lds[buf][2048 + wave * 512]);
  };

  const int nk = K >> 5;
  stage(0, 0);
  for (int ki = 0; ki < nk; ++ki) {
    const int cur = ki & 1;
    __syncthreads();
    if (ki + 1 < nk) stage(cur ^ 1, (ki + 1) << 5);
    bf16x8 af[4], bf[4];
    #pragma unroll
    for (int t = 0; t < 4; ++t)
      af[t] = *(const bf16x8*)&a_lds[cur][(wr + t * 16 + l16) * 32 + quad * 8];
    #pragma unroll
    for (int t = 0; t < 4; ++t)
      bf[t] = *(const bf16x8*)&b_lds[cur][(wc + t * 16 + l16) * 32 + quad * 8];
    #pragma unroll
    for (int mt = 0; mt < 4; ++mt)
      #pragma unroll
      for (int nt = 0; nt < 4; ++nt)
        acc[mt][nt] = __builtin_amdgcn_mfma_f32_16x16x32_bf16(af[mt], bf[nt], acc[mt][nt], 0, 0, 0);
  }

  if (EPI == 0 && bn >= 1024) {
    // pure-V block: vo[b][h][d][n]; r=0..3 are 4 consecutive n at fixed d.
    const int b = bm >> 11;
    #pragma unroll
    for (int mt = 0; mt < 4; ++mt) {
      const int n = (bm + wr + mt * 16 + quad * 4) & (N_ - 1);
      #pragma unroll
      for (int nt = 0; nt < 4; ++nt) {
        const int col = bn + wc + nt * 16 + l16;
        const int h = (col >> 6) & (H_ - 1), d = col & (DH_ - 1);
        u32x2 pkd;
        pkd.x = cvtpk2(acc[mt][nt][0], acc[mt][nt][1]);
        pkd.y = cvtpk2(acc[mt][nt][2], acc[mt][nt][3]);
        *(u32x2*)(vo + ((((size_t)b * H_ + h) * DH_ + d) << 11) + n) = pkd;
      }
    }
  } else {
    #pragma unroll
    for (int mt = 0; mt < 4; ++mt)
      #pragma unroll
      for (int nt = 0; nt < 4; ++nt)
        #pragma unroll
        for (int r = 0; r < 4; ++r)
          epi_store<EPI>(acc[mt][nt][r], bm + wr + mt * 16 + quad * 4 + r,
                         bn + wc + nt * 16 + l16, N,
                         bias, resid, fout, bout, qo, ko, vo);
  }
}

// ---------------- LayerNorm device helper: one wave per token -----------------
__device__ inline void ln_row(const float* __restrict__ xr,
                              const float* __restrict__ w, const float* __restrict__ b,
                              __bf16* __restrict__ orow, int lane)
{
  float4 v0 = ((const float4*)xr)[lane];
  float4 v1 = ((const float4*)xr)[lane + 64];
  float s = v0.x + v0.y + v0.z + v0.w + v1.x + v1.y + v1.z + v1.w;
  float q = v0.x*v0.x + v0.y*v0.y + v0.z*v0.z + v0.w*v0.w
          + v1.x*v1.x + v1.y*v1.y + v1.z*v1.z + v1.w*v1.w;
  #pragma unroll
  for (int off = 32; off >= 1; off >>= 1) {
    s += __shfl_xor(s, off, 64);
    q += __shfl_xor(q, off, 64);
  }
  const float mu  = s * (1.0f / C_);
  const float var = q * (1.0f / C_) - mu * mu;
  const float rs  = rsqrtf(var + 1e-5f);
  float4 w0 = ((const float4*)w)[lane], w1 = ((const float4*)w)[lane + 64];
  float4 b0 = ((const float4*)b)[lane], b1 = ((const float4*)b)[lane + 64];
  const int c0 = lane * 4;
  orow[c0 + 0]       = (__bf16)((v0.x - mu) * rs * w0.x + b0.x);
  orow[c0 + 1]       = (__bf16)((v0.y - mu) * rs * w0.y + b0.y);
  orow[c0 + 2]       = (__bf16)((v0.z - mu) * rs * w0.z + b0.z);
  orow[c0 + 3]       = (__bf16)((v0.w - mu) * rs * w0.w + b0.w);
  orow[256 + c0 + 0] = (__bf16)((v1.x - mu) * rs * w1.x + b1.x);
  orow[256 + c0 + 1] = (__bf16)((v1.y - mu) * rs * w1.y + b1.y);
  orow[256 + c0 + 2] = (__bf16)((v1.z - mu) * rs * w1.z + b1.z);
  orow[256 + c0 + 3] = (__bf16)((v1.w - mu) * rs * w1.w + b1.w);
}

// ---------------- standalone LN (for ln2) -------------------------------------
__global__ __launch_bounds__(256) void ln_kernel(
    const float* __restrict__ x, const float* __restrict__ w,
    const float* __restrict__ b, __bf16* __restrict__ out)
{
  const int wave = threadIdx.x >> 6, lane = threadIdx.x & 63;
  const int tok  = blockIdx.x * 4 + wave;
  ln_row(x + (size_t)tok * C_, w, b, out + (size_t)tok * C_, lane);
}

// ---------------- merged: weight cast (blocks 0..3071) + ln1 (3072..5119) -----
__global__ __launch_bounds__(256) void castln_kernel(
    const float* __restrict__ s0, const float* __restrict__ s1,
    const float* __restrict__ s2, const float* __restrict__ s3,
    __bf16* __restrict__ d0, __bf16* __restrict__ d1,
    __bf16* __restrict__ d2, __bf16* __restrict__ d3,
    const float* __restrict__ x, const float* __restrict__ n1w,
    const float* __restrict__ n1b, __bf16* __restrict__ hbuf)
{
  if (blockIdx.x < 3072) {
    const int i = (blockIdx.x * 256 + threadIdx.x) * 4;
    const float* s; __bf16* d; int off;
    if (i < 786432)       { s = s0; d = d0; off = i; }
    else if (i < 1048576) { s = s1; d = d1; off = i - 786432; }
    else if (i < 2097152) { s = s2; d = d2; off = i - 1048576; }
    else                  { s = s3; d = d3; off = i - 2097152; }
    const float4 v = *(const float4*)(s + off);
    u32x2 pk;
    pk.x = pack2_bf16(v.x, v.y);
    pk.y = pack2_bf16(v.z, v.w);
    *(u32x2*)(d + off) = pk;
  } else {
    const int wave = threadIdx.x >> 6, lane = threadIdx.x & 63;
    const int tok  = (blockIdx.x - 3072) * 4 + wave;
    ln_row(x + (size_t)tok * C_, n1w, n1b, hbuf + (size_t)tok * C_, lane);
  }
}

// ---------------- flash attention v13 (frozen at R4; single 512-block launch) -
// Measured-best flash: 51.3-52.0us, MfmaUtil ~29, VALU ~31, 2 blocks/CU.
// R2 (4w/SIMD): null. R3 (reg-streaming): 2.25x worse. R8 (half-grid): 1.5x
// worse per half. R12 (cast prologue): +4.5us. Frozen.
__global__ __launch_bounds__(256, 2) void flash_kernel(
    const __bf16* __restrict__ qb, const __bf16* __restrict__ kb,
    const __bf16* __restrict__ vtg, const float* __restrict__ rpb,
    __bf16* __restrict__ outb, int bh0)
{
  __shared__ __align__(16) __bf16 kbufs[2][8192];   // [buf][2 ks][128 key(perm)][32 d]
  __shared__ __align__(16) __bf16 vbufs[2][8192];   // [buf][4 ks2][64 d][32 key], swizzled
  __shared__ __align__(16) float  biasF[2192];      // bias[i + boff] * LOG2E, f32
  const int tid  = threadIdx.x;
  const int wave = tid >> 6, lane = tid & 63;
  const int quad = lane >> 4, l16 = lane & 15;
  const int bh = blockIdx.y + bh0, h = bh & (H_ - 1);
  const int q0 = blockIdx.x * 128;
  const int boff = 1920 - q0;

  for (int i = tid; i < 2192; i += 256) {
    int ridx = i + boff;
    ridx = ridx < 0 ? 0 : (ridx > 2 * N_ - 2 ? 2 * N_ - 2 : ridx);
    biasF[i] = rpb[(size_t)ridx * H_ + h] * LOG2E;
  }

  const __bf16* qptr = qb  + (size_t)bh * N_ * DH_;
  const __bf16* kptr = kb  + (size_t)bh * N_ * DH_;
  const __bf16* vtp  = vtg + (size_t)bh * N_ * DH_;

  bf16x8 qf[2][2];
  #pragma unroll
  for (int mt = 0; mt < 2; ++mt)
    #pragma unroll
    for (int ks = 0; ks < 2; ++ks)
      qf[mt][ks] = *(const bf16x8*)(qptr +
          (size_t)(q0 + wave * 32 + mt * 16 + l16) * DH_ + ks * 32 + quad * 8);

  const f32x4 fzero = {0.f, 0.f, 0.f, 0.f};
  f32x4 o[2][4];
  f32x4 la[2] = {fzero, fzero};     // l accumulators (ones-MFMA)
  #pragma unroll
  for (int mt = 0; mt < 2; ++mt)
    #pragma unroll
    for (int dt = 0; dt < 4; ++dt) o[mt][dt] = fzero;

  const s16x8 ones_s = {(short)0x3F80, (short)0x3F80, (short)0x3F80, (short)0x3F80,
                        (short)0x3F80, (short)0x3F80, (short)0x3F80, (short)0x3F80};
  const bf16x8 ones8 = __builtin_bit_cast(bf16x8, ones_s);

  const int slr = lane >> 2;
  const int slc = lane & 3;
  const int vswz = (slr & 3) ^ ((slr >> 2) & 3);
  const int rswz = (l16 & 3) ^ ((l16 >> 2) & 3);

  auto stageK = [&](int buf, int kcn) {
    #pragma unroll
    for (int j = 0; j < 4; ++j) {
      const int idx = wave * 4 + j;
      const int ks = idx & 1, g = idx >> 1;
      // permuted source row: within each 32-key group, LDS row m holds global
      // key [b3 b2 b4 b1 b0] so that S-tile pairs yield x32 B-frag key order.
      const int R = g * 16 + slr;
      const int m = R & 31;
      const int pr = (R & ~31) | (((m >> 2) & 3) << 3) | (((m >> 4) & 1) << 2) | (m & 3);
      gld_lds16(kptr + (size_t)(kcn + pr) * DH_ + ks * 32 + slc * 8,
                &kbufs[buf][ks * 4096 + g * 512]);
    }
  };
  auto stageV = [&](int buf, int kcn) {
    #pragma unroll
    for (int j = 0; j < 4; ++j) {
      const int idx = wave * 4 + j;
      const int ks2 = idx & 3, gg = idx >> 2;
      gld_lds16(vtp + (size_t)(gg * 16 + slr) * N_ + kcn + ks2 * 32 + (slc ^ vswz) * 8,
                &vbufs[buf][ks2 * 2048 + gg * 512]);
    }
  };

  const int bb0 = 127 + quad * 8 - wave * 32 - l16;   // permuted-key bias base

  stageK(0, 0);
  stageV(0, 0);
  for (int it = 0; it < 16; ++it) {
    const int cur = it & 1;
    const int kc = it << 7;
    __syncthreads();   // buf[cur] DMA complete; buf[cur] reads of iter it-2 done
    if (it < 15) {
      stageK(cur ^ 1, kc + 128);
      stageV(cur ^ 1, kc + 128);
    }

    // V-frag issue-early: depends only on the barrier; lands during QK/softmax.
    bf16x8 vv[16];
    #pragma unroll
    for (int c = 0; c < 4; ++c)
      #pragma unroll
      for (int dt = 0; dt < 4; ++dt)
        vv[c * 4 + dt] = *(const bf16x8*)&vbufs[cur][c * 2048 + l16 * 32 +
                                                     (quad ^ rswz) * 8 + dt * 512];

    unsigned pk[2][8][2];
    const float* bp = biasF + kc + bb0;
    #pragma unroll
    for (int ct = 0; ct < 8; ++ct) {
      // permuted global key for (ct, quad, r): kc + (ct>>1)*32 + (ct&1)*4 + quad*8 + r
      const int co = (ct >> 1) * 32 + (ct & 1) * 4;
      const bf16x8 kf0 = *(const bf16x8*)&kbufs[cur][(ct * 16 + l16) * 32 + quad * 8];
      const bf16x8 kf1 = *(const bf16x8*)&kbufs[cur][4096 + (ct * 16 + l16) * 32 + quad * 8];
      const f32x4 c0 = {bp[co], bp[co + 1], bp[co + 2], bp[co + 3]};
      const f32x4 c1 = {bp[co - 16], bp[co - 15], bp[co - 14], bp[co - 13]};
      f32x4 s0 = __builtin_amdgcn_mfma_f32_16x16x32_bf16(kf0, qf[0][0], c0, 0, 0, 0);
      s0 = __builtin_amdgcn_mfma_f32_16x16x32_bf16(kf1, qf[0][1], s0, 0, 0, 0);
      f32x4 s1 = __builtin_amdgcn_mfma_f32_16x16x32_bf16(kf0, qf[1][0], c1, 0, 0, 0);
      s1 = __builtin_amdgcn_mfma_f32_16x16x32_bf16(kf1, qf[1][1], s1, 0, 0, 0);
      {
        const float p0 = __builtin_amdgcn_exp2f(s0[0]);
        const float p1 = __builtin_amdgcn_exp2f(s0[1]);
        const float p2 = __builtin_amdgcn_exp2f(s0[2]);
        const float p3 = __builtin_amdgcn_exp2f(s0[3]);
        pk[0][ct][0] = cvtpk2(p0, p1);
        pk[0][ct][1] = cvtpk2(p2, p3);
      }
      {
        const float p0 = __builtin_amdgcn_exp2f(s1[0]);
        const float p1 = __builtin_amdgcn_exp2f(s1[1]);
        const float p2 = __builtin_amdgcn_exp2f(s1[2]);
        const float p3 = __builtin_amdgcn_exp2f(s1[3]);
        pk[1][ct][0] = cvtpk2(p0, p1);
        pk[1][ct][1] = cvtpk2(p2, p3);
      }
    }

    // PV + l-accum on 16x16x32: pf8 = [tileA r0..3 | tileB r0..3] = keys quad*8+0..7
    #pragma unroll
    for (int c = 0; c < 4; ++c) {
      const u32x4 t0 = {pk[0][2*c][0], pk[0][2*c][1], pk[0][2*c+1][0], pk[0][2*c+1][1]};
      const u32x4 t1 = {pk[1][2*c][0], pk[1][2*c][1], pk[1][2*c+1][0], pk[1][2*c+1][1]};
      const bf16x8 pf0 = __builtin_bit_cast(bf16x8, t0);
      const bf16x8 pf1 = __builtin_bit_cast(bf16x8, t1);
      la[0] = __builtin_amdgcn_mfma_f32_16x16x32_bf16(ones8, pf0, la[0], 0, 0, 0);
      la[1] = __builtin_amdgcn_mfma_f32_16x16x32_bf16(ones8, pf1, la[1], 0, 0, 0);
      #pragma unroll
      for (int dt = 0; dt < 4; ++dt) {
        const bf16x8 vf = vv[c * 4 + dt];
        o[0][dt] = __builtin_amdgcn_mfma_f32_16x16x32_bf16(vf, pf0, o[0][dt], 0, 0, 0);
        o[1][dt] = __builtin_amdgcn_mfma_f32_16x16x32_bf16(vf, pf1, o[1][dt], 0, 0, 0);
      }
    }
  }

  const int b = bh >> 3;
  #pragma unroll
  for (int mt = 0; mt < 2; ++mt) {
    const float inv = 1.0f / la[mt][0];
    const int qg = q0 + wave * 32 + mt * 16 + l16;
    __bf16* orow = outb + ((size_t)(b * N_ + qg)) * C_ + h * DH_ + quad * 4;
    #pragma unroll
    for (int dt = 0; dt < 4; ++dt) {
      u32x2 pkd;
      pkd.x = cvtpk2(o[mt][dt][0] * inv, o[mt][dt][1] * inv);
      pkd.y = cvtpk2(o[mt][dt][2] * inv, o[mt][dt][3] * inv);
      *(u32x2*)(orow + dt * 16) = pkd;
    }
  }
}

extern "C" void kernel_launch(void* const* d_in, const int* in_sizes, int n_in,
                              void* d_out, int out_size, void* d_ws, size_t ws_size,
                              hipStream_t stream)
{
  const float* x      = (const float*)d_in[0];
  const float* qkv_w  = (const float*)d_in[1];
  const float* proj_w = (const float*)d_in[2];
  const float* proj_b = (const float*)d_in[3];
  const float* rpb    = (const float*)d_in[4];
  const float* n1w    = (const float*)d_in[5];
  const float* n1b    = (const float*)d_in[6];
  const float* n2w    = (const float*)d_in[7];
  const float* n2b    = (const float*)d_in[8];
  const float* fc1_w  = (const float*)d_in[9];
  const float* fc1_b  = (const float*)d_in[10];
  const float* fc2_w  = (const float*)d_in[11];
  const float* fc2_b  = (const float*)d_in[12];

  char* ws = (char*)d_ws;
  __bf16* hbuf = (__bf16*)(ws + 0);          // 8192*512  bf16
  __bf16* qbuf = (__bf16*)(ws + 8388608);    // [b,h,n,d] (pre-scaled by QSCALE)
  __bf16* kbuf = (__bf16*)(ws + 16777216);   // [b,h,n,d]
  __bf16* vbuf = (__bf16*)(ws + 25165824);   // V^T [b,h,d,n]
  __bf16* gelu = (__bf16*)(ws + 0);          // 8192*2048 bf16 (alias)
  __bf16* wq   = (__bf16*)(ws + 33554432);
  __bf16* wp   = (__bf16*)(ws + 35127296);
  __bf16* w1   = (__bf16*)(ws + 35651584);
  __bf16* w2   = (__bf16*)(ws + 37748736);
  __bf16* attn = (__bf16*)(ws + 39845888);   // 8192*512 bf16
  __bf16* h2in = attn;                       // alias
  float*  x1   = (float*)(ws + 48234496);    // 8192*512 fp32
  float*  outp = (float*)d_out;

  // cast (3072 blocks) + ln1 (2048 blocks) in one launch
  castln_kernel<<<5120, 256, 0, stream>>>(qkv_w, proj_w, fc1_w, fc2_w,
      wq, wp, w1, w2, x, n1w, n1b, hbuf);

  gemm256<0><<<dim3(64, 12), 256, 0, stream>>>(hbuf, wq, MTOK, 1536, 512,
      nullptr, nullptr, nullptr, nullptr, qbuf, kbuf, vbuf);

  flash_kernel<<<dim3(16, 32), 256, 0, stream>>>(qbuf, kbuf, vbuf, rpb, attn, 0);

  gemm512<1, 64><<<dim3(64, 8), 512, 0, stream>>>(attn, wp, MTOK, 512, 512,
      proj_b, x, x1, nullptr, nullptr, nullptr, nullptr);

  ln_kernel<<<2048, 256, 0, stream>>>(x1, n2w, n2b, h2in);

  gemm256<2><<<dim3(64, 16), 256, 0, stream>>>(h2in, w1, MTOK, 2048, 512,
      fc1_b, nullptr, nullptr, gelu, nullptr, nullptr, nullptr);

  gemm512<1, 64><<<dim3(64, 8), 512, 0, stream>>>(gelu, w2, MTOK, 512, 2048,
      fc2_b, x1, outp, nullptr, nullptr, nullptr, nullptr);
}